// Round 1
// baseline (533.584 us; speedup 1.0000x reference)
//
#include <hip/hip_runtime.h>
#include <stdint.h>

#define NCH 128          // C_IN == C_OUT == 128
#define WAVE 64

// ---------------------------------------------------------------------------
// Detect whether edge_index buffer is int64 (odd int32 words all zero) or int32.
// Deterministic given inputs. Values are in [0, 50000) so int64 high words == 0.
// ---------------------------------------------------------------------------
__global__ void detect_idx64_kernel(const int* __restrict__ ei, int* __restrict__ flag) {
    if (blockIdx.x == 0 && threadIdx.x == 0) {
        int nz = 0;
        for (int i = 0; i < 128; ++i) nz |= ei[2 * i + 1];
        *flag = (nz == 0) ? 1 : 0;
    }
}

__device__ __forceinline__ int load_row(const int* ei, int E, int e, bool is64) {
    return is64 ? ei[2 * (size_t)e] : ei[e];
}
__device__ __forceinline__ int load_col(const int* ei, int E, int e, bool is64) {
    return is64 ? ei[2 * (size_t)E + 2 * (size_t)e] : ei[(size_t)E + e];
}

// ---------------------------------------------------------------------------
// Histogram of target (col) nodes.
// ---------------------------------------------------------------------------
__global__ void histo_kernel(const int* __restrict__ ei, int E,
                             const int* __restrict__ flag, int* __restrict__ deg) {
    const bool is64 = (*flag != 0);
    int i = blockIdx.x * blockDim.x + threadIdx.x;
    const int stride = gridDim.x * blockDim.x;
    for (; i < E; i += stride) {
        int c = load_col(ei, E, i, is64);
        atomicAdd(&deg[c], 1);
    }
}

// ---------------------------------------------------------------------------
// Single-block exclusive scan of deg -> offsets, init cursors, compute
// dinv[i] = rsqrt(deg[i] + 1)  (+1 for the self-loop).
// ---------------------------------------------------------------------------
__global__ __launch_bounds__(1024) void scan_prep_kernel(const int* __restrict__ deg, int N,
                                                         int* __restrict__ offsets,
                                                         int* __restrict__ cur,
                                                         float* __restrict__ dinv) {
    __shared__ int lsum[1024];
    const int t = threadIdx.x;
    const int chunk = (N + 1023) / 1024;
    const int lo = t * chunk;
    const int hi = min(lo + chunk, N);
    int s = 0;
    for (int i = lo; i < hi; ++i) s += deg[i];
    lsum[t] = s;
    __syncthreads();
    // Hillis-Steele inclusive scan over 1024 partials
    for (int d = 1; d < 1024; d <<= 1) {
        int v = (t >= d) ? lsum[t - d] : 0;
        __syncthreads();
        lsum[t] += v;
        __syncthreads();
    }
    int running = lsum[t] - s;  // exclusive prefix of this thread's chunk
    for (int i = lo; i < hi; ++i) {
        offsets[i] = running;
        cur[i] = running;
        int d = deg[i];
        dinv[i] = rsqrtf((float)(d + 1));
        running += d;
    }
    if (t == 1023) offsets[N] = running;  // == E (threads past end carry total)
}

// ---------------------------------------------------------------------------
// Scatter edges into CSR order (by target), precomputing the edge norm.
// entry = { src_row, bitcast(norm) }
// ---------------------------------------------------------------------------
__global__ void build_csr_kernel(const int* __restrict__ ei, int E,
                                 const int* __restrict__ flag,
                                 const float* __restrict__ dinv,
                                 int* __restrict__ cur, int2* __restrict__ entries) {
    const bool is64 = (*flag != 0);
    int i = blockIdx.x * blockDim.x + threadIdx.x;
    const int stride = gridDim.x * blockDim.x;
    for (; i < E; i += stride) {
        int r = load_row(ei, E, i, is64);
        int c = load_col(ei, E, i, is64);
        float nrm = dinv[r] * dinv[c];
        int pos = atomicAdd(&cur[c], 1);
        entries[pos] = make_int2(r, __float_as_int(nrm));
    }
}

// ---------------------------------------------------------------------------
// h = x @ W.  Full W (128x128 f32 = 64 KiB) staged in LDS.
// Block = 256 threads (4 waves); each wave computes 4 rows; lane handles
// cols {2*lane, 2*lane+1} (float2) -> 8 FMA per ds_read_b64, LDS not limiting.
// ---------------------------------------------------------------------------
__global__ __launch_bounds__(256) void gemm_xw_kernel(const float* __restrict__ x,
                                                      const float* __restrict__ W,
                                                      float* __restrict__ h, int N) {
    __shared__ float sW[NCH * NCH];
    for (int i = threadIdx.x * 4; i < NCH * NCH; i += blockDim.x * 4) {
        *reinterpret_cast<float4*>(&sW[i]) = *reinterpret_cast<const float4*>(&W[i]);
    }
    __syncthreads();

    const int wave = threadIdx.x >> 6;
    const int lane = threadIdx.x & 63;
    const int r0 = (blockIdx.x * 4 + wave) * 4;
    if (r0 >= N) return;

    const int ra = min(r0 + 0, N - 1);
    const int rb = min(r0 + 1, N - 1);
    const int rc = min(r0 + 2, N - 1);
    const int rd = min(r0 + 3, N - 1);
    const float* x0 = x + (size_t)ra * NCH;
    const float* x1 = x + (size_t)rb * NCH;
    const float* x2 = x + (size_t)rc * NCH;
    const float* x3 = x + (size_t)rd * NCH;

    float a0x = 0.f, a0y = 0.f, a1x = 0.f, a1y = 0.f;
    float a2x = 0.f, a2y = 0.f, a3x = 0.f, a3y = 0.f;

    #pragma unroll 8
    for (int kk = 0; kk < NCH; kk += 4) {
        const float4 xa = *reinterpret_cast<const float4*>(x0 + kk);
        const float4 xb = *reinterpret_cast<const float4*>(x1 + kk);
        const float4 xc = *reinterpret_cast<const float4*>(x2 + kk);
        const float4 xd = *reinterpret_cast<const float4*>(x3 + kk);
        const float2* wrow = reinterpret_cast<const float2*>(&sW[(size_t)kk * NCH]) + lane;

        float2 w;
        w = wrow[0];
        a0x += xa.x * w.x; a0y += xa.x * w.y;
        a1x += xb.x * w.x; a1y += xb.x * w.y;
        a2x += xc.x * w.x; a2y += xc.x * w.y;
        a3x += xd.x * w.x; a3y += xd.x * w.y;
        w = wrow[NCH / 2];
        a0x += xa.y * w.x; a0y += xa.y * w.y;
        a1x += xb.y * w.x; a1y += xb.y * w.y;
        a2x += xc.y * w.x; a2y += xc.y * w.y;
        a3x += xd.y * w.x; a3y += xd.y * w.y;
        w = wrow[2 * (NCH / 2)];
        a0x += xa.z * w.x; a0y += xa.z * w.y;
        a1x += xb.z * w.x; a1y += xb.z * w.y;
        a2x += xc.z * w.x; a2y += xc.z * w.y;
        a3x += xd.z * w.x; a3y += xd.z * w.y;
        w = wrow[3 * (NCH / 2)];
        a0x += xa.w * w.x; a0y += xa.w * w.y;
        a1x += xb.w * w.x; a1y += xb.w * w.y;
        a2x += xc.w * w.x; a2y += xc.w * w.y;
        a3x += xd.w * w.x; a3y += xd.w * w.y;
    }

    const int c0 = 2 * lane;
    if (r0 + 0 < N) { h[(size_t)(r0 + 0) * NCH + c0] = a0x; h[(size_t)(r0 + 0) * NCH + c0 + 1] = a0y; }
    if (r0 + 1 < N) { h[(size_t)(r0 + 1) * NCH + c0] = a1x; h[(size_t)(r0 + 1) * NCH + c0 + 1] = a1y; }
    if (r0 + 2 < N) { h[(size_t)(r0 + 2) * NCH + c0] = a2x; h[(size_t)(r0 + 2) * NCH + c0 + 1] = a2y; }
    if (r0 + 3 < N) { h[(size_t)(r0 + 3) * NCH + c0] = a3x; h[(size_t)(r0 + 3) * NCH + c0 + 1] = a3y; }
}

// ---------------------------------------------------------------------------
// SpMM: one wave per target node. lane holds cols {2*lane, 2*lane+1} (float2).
// acc = dinv[n]^2 * h[n]  (self-loop)  + sum_e norm_e * h[src_e]; +bias, ReLU.
// No atomics; 512 B coalesced gather per edge.
// ---------------------------------------------------------------------------
__global__ __launch_bounds__(256) void spmm_csr_kernel(const float* __restrict__ h,
                                                       const int2* __restrict__ entries,
                                                       const int* __restrict__ offsets,
                                                       const float* __restrict__ dinv,
                                                       const float* __restrict__ bias,
                                                       float* __restrict__ out, int N) {
    const int lane = threadIdx.x & 63;
    const int n = blockIdx.x * 4 + (threadIdx.x >> 6);
    if (n >= N) return;

    const float s = dinv[n];
    const float sn = s * s;
    const float2 v = reinterpret_cast<const float2*>(h + (size_t)n * NCH)[lane];
    float ax = sn * v.x;
    float ay = sn * v.y;

    const int beg = offsets[n];
    const int end = offsets[n + 1];
    for (int i = beg; i < end; ++i) {
        const int2 e = entries[i];
        const float nrm = __int_as_float(e.y);
        const float2 u = reinterpret_cast<const float2*>(h + (size_t)e.x * NCH)[lane];
        ax += nrm * u.x;
        ay += nrm * u.y;
    }

    const float2 bb = reinterpret_cast<const float2*>(bias)[lane];
    ax = fmaxf(ax + bb.x, 0.f);
    ay = fmaxf(ay + bb.y, 0.f);
    float2 o; o.x = ax; o.y = ay;
    reinterpret_cast<float2*>(out + (size_t)n * NCH)[lane] = o;
}

// ---------------------------------------------------------------------------
extern "C" void kernel_launch(void* const* d_in, const int* in_sizes, int n_in,
                              void* d_out, int out_size, void* d_ws, size_t ws_size,
                              hipStream_t stream) {
    const float* x = (const float*)d_in[0];
    const int* ei = (const int*)d_in[1];  // int32 view; int64 handled via flag
    const float* W = (const float*)d_in[2];
    const float* bias = (const float*)d_in[3];
    float* out = (float*)d_out;

    const int N = in_sizes[0] / NCH;       // 50000
    const int E = in_sizes[1] / 2;         // 1600000 (element count, dtype-agnostic)

    // Workspace layout (element counts padded to multiples of 128 -> 512B align)
    char* w = (char*)d_ws;
    const int padN = (N + 127) & ~127;
    const int padN1 = (N + 1 + 127) & ~127;
    int* deg = (int*)w;                     w += (size_t)padN * 4;
    int* offsets = (int*)w;                 w += (size_t)padN1 * 4;
    int* cur = (int*)w;                     w += (size_t)padN * 4;
    float* dinv = (float*)w;                w += (size_t)padN * 4;
    int* flag = (int*)w;                    w += 512;
    float* h = (float*)w;                   w += (size_t)N * NCH * 4;
    int2* entries = (int2*)w;               w += (size_t)E * 8;
    (void)ws_size;

    hipMemsetAsync(deg, 0, (size_t)N * 4, stream);
    detect_idx64_kernel<<<1, 64, 0, stream>>>(ei, flag);

    histo_kernel<<<2048, 256, 0, stream>>>(ei, E, flag, deg);
    scan_prep_kernel<<<1, 1024, 0, stream>>>(deg, N, offsets, cur, dinv);
    build_csr_kernel<<<2048, 256, 0, stream>>>(ei, E, flag, dinv, cur, entries);

    gemm_xw_kernel<<<(N + 15) / 16, 256, 0, stream>>>(x, W, h, N);

    spmm_csr_kernel<<<(N + 3) / 4, 256, 0, stream>>>(h, entries, offsets, dinv, bias, out, N);
}

// Round 2
// 451.652 us; speedup vs baseline: 1.1814x; 1.1814x over previous
//
#include <hip/hip_runtime.h>
#include <hip/hip_fp16.h>
#include <stdint.h>

#define NCH 128          // C_IN == C_OUT == 128

// ---------------------------------------------------------------------------
// bf16 helpers (manual RNE pack; decode via bit shift)
// ---------------------------------------------------------------------------
__device__ __forceinline__ unsigned short f2bf(float f) {
    union { float f; uint32_t u; } v; v.f = f;
    uint32_t u = v.u;
    uint32_t r = u + 0x7fffu + ((u >> 16) & 1u);
    return (unsigned short)(r >> 16);
}
__device__ __forceinline__ float bflo(uint32_t u) { return __uint_as_float(u << 16); }
__device__ __forceinline__ float bfhi(uint32_t u) { return __uint_as_float(u & 0xffff0000u); }

// ---------------------------------------------------------------------------
// Detect whether edge_index buffer is int64 (odd int32 words all zero) or int32.
// Deterministic given inputs. Values are in [0, 50000) so int64 high words == 0.
// ---------------------------------------------------------------------------
__global__ void detect_idx64_kernel(const int* __restrict__ ei, int* __restrict__ flag) {
    if (blockIdx.x == 0 && threadIdx.x == 0) {
        int nz = 0;
        for (int i = 0; i < 128; ++i) nz |= ei[2 * i + 1];
        *flag = (nz == 0) ? 1 : 0;
    }
}

__device__ __forceinline__ int load_row(const int* ei, int E, int e, bool is64) {
    return is64 ? ei[2 * (size_t)e] : ei[e];
}
__device__ __forceinline__ int load_col(const int* ei, int E, int e, bool is64) {
    return is64 ? ei[2 * (size_t)E + 2 * (size_t)e] : ei[(size_t)E + e];
}

// ---------------------------------------------------------------------------
// Histogram of target (col) nodes.
// ---------------------------------------------------------------------------
__global__ void histo_kernel(const int* __restrict__ ei, int E,
                             const int* __restrict__ flag, int* __restrict__ deg) {
    const bool is64 = (*flag != 0);
    int i = blockIdx.x * blockDim.x + threadIdx.x;
    const int stride = gridDim.x * blockDim.x;
    for (; i < E; i += stride) {
        int c = load_col(ei, E, i, is64);
        atomicAdd(&deg[c], 1);
    }
}

// ---------------------------------------------------------------------------
// Single-block exclusive scan of deg -> offsets, init cursors, compute
// dinv[i] = rsqrt(deg[i] + 1)  (+1 for the self-loop).
// ---------------------------------------------------------------------------
__global__ __launch_bounds__(1024) void scan_prep_kernel(const int* __restrict__ deg, int N,
                                                         int* __restrict__ offsets,
                                                         int* __restrict__ cur,
                                                         float* __restrict__ dinv) {
    __shared__ int lsum[1024];
    const int t = threadIdx.x;
    const int chunk = (N + 1023) / 1024;
    const int lo = t * chunk;
    const int hi = min(lo + chunk, N);
    int s = 0;
    for (int i = lo; i < hi; ++i) s += deg[i];
    lsum[t] = s;
    __syncthreads();
    for (int d = 1; d < 1024; d <<= 1) {
        int v = (t >= d) ? lsum[t - d] : 0;
        __syncthreads();
        lsum[t] += v;
        __syncthreads();
    }
    int running = lsum[t] - s;  // exclusive prefix of this thread's chunk
    for (int i = lo; i < hi; ++i) {
        offsets[i] = running;
        cur[i] = running;
        int d = deg[i];
        dinv[i] = rsqrtf((float)(d + 1));
        running += d;
    }
    if (t == 1023) offsets[N] = running;  // == E
}

// ---------------------------------------------------------------------------
// Scatter edges into CSR order (by target). Entry packs {src:16 | fp16 norm:16}.
// Requires N < 65536 (N = 50000 here).
// ---------------------------------------------------------------------------
__global__ void build_csr_kernel(const int* __restrict__ ei, int E,
                                 const int* __restrict__ flag,
                                 const float* __restrict__ dinv,
                                 int* __restrict__ cur, uint32_t* __restrict__ entries) {
    const bool is64 = (*flag != 0);
    int i = blockIdx.x * blockDim.x + threadIdx.x;
    const int stride = gridDim.x * blockDim.x;
    for (; i < E; i += stride) {
        int r = load_row(ei, E, i, is64);
        int c = load_col(ei, E, i, is64);
        float nrm = dinv[r] * dinv[c];
        uint32_t packed = (uint32_t)r |
            ((uint32_t)__half_as_ushort(__float2half(nrm)) << 16);
        int pos = atomicAdd(&cur[c], 1);
        entries[pos] = packed;
    }
}

// ---------------------------------------------------------------------------
// h = x @ W (f32 compute), stored as bf16. W (64 KiB) staged in LDS.
// Block = 256 threads (4 waves); each wave computes 4 rows; lane handles
// cols {2*lane, 2*lane+1}.
// ---------------------------------------------------------------------------
__global__ __launch_bounds__(256) void gemm_xw_kernel(const float* __restrict__ x,
                                                      const float* __restrict__ W,
                                                      uint32_t* __restrict__ hb, int N) {
    __shared__ float sW[NCH * NCH];
    for (int i = threadIdx.x * 4; i < NCH * NCH; i += blockDim.x * 4) {
        *reinterpret_cast<float4*>(&sW[i]) = *reinterpret_cast<const float4*>(&W[i]);
    }
    __syncthreads();

    const int wave = threadIdx.x >> 6;
    const int lane = threadIdx.x & 63;
    const int r0 = (blockIdx.x * 4 + wave) * 4;
    if (r0 >= N) return;

    const int ra = min(r0 + 0, N - 1);
    const int rb = min(r0 + 1, N - 1);
    const int rc = min(r0 + 2, N - 1);
    const int rd = min(r0 + 3, N - 1);
    const float* x0 = x + (size_t)ra * NCH;
    const float* x1 = x + (size_t)rb * NCH;
    const float* x2 = x + (size_t)rc * NCH;
    const float* x3 = x + (size_t)rd * NCH;

    float a0x = 0.f, a0y = 0.f, a1x = 0.f, a1y = 0.f;
    float a2x = 0.f, a2y = 0.f, a3x = 0.f, a3y = 0.f;

    #pragma unroll 8
    for (int kk = 0; kk < NCH; kk += 4) {
        const float4 xa = *reinterpret_cast<const float4*>(x0 + kk);
        const float4 xb = *reinterpret_cast<const float4*>(x1 + kk);
        const float4 xc = *reinterpret_cast<const float4*>(x2 + kk);
        const float4 xd = *reinterpret_cast<const float4*>(x3 + kk);
        const float2* wrow = reinterpret_cast<const float2*>(&sW[(size_t)kk * NCH]) + lane;

        float2 w;
        w = wrow[0];
        a0x += xa.x * w.x; a0y += xa.x * w.y;
        a1x += xb.x * w.x; a1y += xb.x * w.y;
        a2x += xc.x * w.x; a2y += xc.x * w.y;
        a3x += xd.x * w.x; a3y += xd.x * w.y;
        w = wrow[NCH / 2];
        a0x += xa.y * w.x; a0y += xa.y * w.y;
        a1x += xb.y * w.x; a1y += xb.y * w.y;
        a2x += xc.y * w.x; a2y += xc.y * w.y;
        a3x += xd.y * w.x; a3y += xd.y * w.y;
        w = wrow[2 * (NCH / 2)];
        a0x += xa.z * w.x; a0y += xa.z * w.y;
        a1x += xb.z * w.x; a1y += xb.z * w.y;
        a2x += xc.z * w.x; a2y += xc.z * w.y;
        a3x += xd.z * w.x; a3y += xd.z * w.y;
        w = wrow[3 * (NCH / 2)];
        a0x += xa.w * w.x; a0y += xa.w * w.y;
        a1x += xb.w * w.x; a1y += xb.w * w.y;
        a2x += xc.w * w.x; a2y += xc.w * w.y;
        a3x += xd.w * w.x; a3y += xd.w * w.y;
    }

    // Pack pairs {2*lane, 2*lane+1} to bf16 and store 4 B per lane per row.
    const uint32_t p0 = (uint32_t)f2bf(a0x) | ((uint32_t)f2bf(a0y) << 16);
    const uint32_t p1 = (uint32_t)f2bf(a1x) | ((uint32_t)f2bf(a1y) << 16);
    const uint32_t p2 = (uint32_t)f2bf(a2x) | ((uint32_t)f2bf(a2y) << 16);
    const uint32_t p3 = (uint32_t)f2bf(a3x) | ((uint32_t)f2bf(a3y) << 16);
    if (r0 + 0 < N) hb[(size_t)(r0 + 0) * (NCH / 2) + lane] = p0;
    if (r0 + 1 < N) hb[(size_t)(r0 + 1) * (NCH / 2) + lane] = p1;
    if (r0 + 2 < N) hb[(size_t)(r0 + 2) * (NCH / 2) + lane] = p2;
    if (r0 + 3 < N) hb[(size_t)(r0 + 3) * (NCH / 2) + lane] = p3;
}

// ---------------------------------------------------------------------------
// SpMM: one wave per target node, split into two 32-lane halves.
// Each half owns half the node's edge list; lane covers 4 cols (bf16x4 = 8 B).
// 4-deep manual unroll -> up to 8 independent gathers in flight per wave.
// Halves combined via one __shfl_xor(...,32); f32 accumulate; +bias, ReLU.
// ---------------------------------------------------------------------------
__global__ __launch_bounds__(256) void spmm_csr_kernel(const uint32_t* __restrict__ hb,
                                                       const uint32_t* __restrict__ entries,
                                                       const int* __restrict__ offsets,
                                                       const float* __restrict__ dinv,
                                                       const float* __restrict__ bias,
                                                       float* __restrict__ out, int N) {
    const int lane = threadIdx.x & 63;
    const int n = blockIdx.x * 4 + (threadIdx.x >> 6);
    if (n >= N) return;

    const int half = lane >> 5;
    const int sl = lane & 31;          // covers cols sl*4 .. sl*4+3

    const int beg = offsets[n];
    const int end = offsets[n + 1];
    const int len = end - beg;
    const int mid = beg + ((len + 1) >> 1);
    int i = half ? mid : beg;
    const int ie = half ? end : mid;

    float a0 = 0.f, a1 = 0.f, a2 = 0.f, a3 = 0.f;

    for (; i + 3 < ie; i += 4) {
        const uint32_t e0 = entries[i + 0];
        const uint32_t e1 = entries[i + 1];
        const uint32_t e2 = entries[i + 2];
        const uint32_t e3 = entries[i + 3];
        const uint2 u0 = *reinterpret_cast<const uint2*>(hb + (size_t)(e0 & 0xffffu) * (NCH / 2) + sl * 2);
        const uint2 u1 = *reinterpret_cast<const uint2*>(hb + (size_t)(e1 & 0xffffu) * (NCH / 2) + sl * 2);
        const uint2 u2 = *reinterpret_cast<const uint2*>(hb + (size_t)(e2 & 0xffffu) * (NCH / 2) + sl * 2);
        const uint2 u3 = *reinterpret_cast<const uint2*>(hb + (size_t)(e3 & 0xffffu) * (NCH / 2) + sl * 2);
        const float n0 = __half2float(__ushort_as_half((unsigned short)(e0 >> 16)));
        const float n1 = __half2float(__ushort_as_half((unsigned short)(e1 >> 16)));
        const float n2 = __half2float(__ushort_as_half((unsigned short)(e2 >> 16)));
        const float n3 = __half2float(__ushort_as_half((unsigned short)(e3 >> 16)));
        a0 += n0 * bflo(u0.x); a1 += n0 * bfhi(u0.x); a2 += n0 * bflo(u0.y); a3 += n0 * bfhi(u0.y);
        a0 += n1 * bflo(u1.x); a1 += n1 * bfhi(u1.x); a2 += n1 * bflo(u1.y); a3 += n1 * bfhi(u1.y);
        a0 += n2 * bflo(u2.x); a1 += n2 * bfhi(u2.x); a2 += n2 * bflo(u2.y); a3 += n2 * bfhi(u2.y);
        a0 += n3 * bflo(u3.x); a1 += n3 * bfhi(u3.x); a2 += n3 * bflo(u3.y); a3 += n3 * bfhi(u3.y);
    }
    for (; i < ie; ++i) {
        const uint32_t e0 = entries[i];
        const uint2 u0 = *reinterpret_cast<const uint2*>(hb + (size_t)(e0 & 0xffffu) * (NCH / 2) + sl * 2);
        const float n0 = __half2float(__ushort_as_half((unsigned short)(e0 >> 16)));
        a0 += n0 * bflo(u0.x); a1 += n0 * bfhi(u0.x); a2 += n0 * bflo(u0.y); a3 += n0 * bfhi(u0.y);
    }

    // combine the two halves (each lane ends with the full edge sum for its cols)
    a0 += __shfl_xor(a0, 32);
    a1 += __shfl_xor(a1, 32);
    a2 += __shfl_xor(a2, 32);
    a3 += __shfl_xor(a3, 32);

    // self-loop: dinv[n]^2 * h[n]
    const float s = dinv[n];
    const float sn = s * s;
    const uint2 us = *reinterpret_cast<const uint2*>(hb + (size_t)n * (NCH / 2) + sl * 2);
    a0 += sn * bflo(us.x); a1 += sn * bfhi(us.x); a2 += sn * bflo(us.y); a3 += sn * bfhi(us.y);

    if (half == 0) {
        const float4 bb = reinterpret_cast<const float4*>(bias)[sl];
        float4 o;
        o.x = fmaxf(a0 + bb.x, 0.f);
        o.y = fmaxf(a1 + bb.y, 0.f);
        o.z = fmaxf(a2 + bb.z, 0.f);
        o.w = fmaxf(a3 + bb.w, 0.f);
        reinterpret_cast<float4*>(out + (size_t)n * NCH)[sl] = o;
    }
}

// ---------------------------------------------------------------------------
extern "C" void kernel_launch(void* const* d_in, const int* in_sizes, int n_in,
                              void* d_out, int out_size, void* d_ws, size_t ws_size,
                              hipStream_t stream) {
    const float* x = (const float*)d_in[0];
    const int* ei = (const int*)d_in[1];  // int32 view; int64 handled via flag
    const float* W = (const float*)d_in[2];
    const float* bias = (const float*)d_in[3];
    float* out = (float*)d_out;

    const int N = in_sizes[0] / NCH;       // 50000
    const int E = in_sizes[1] / 2;         // 1600000

    char* w = (char*)d_ws;
    const int padN = (N + 127) & ~127;
    const int padN1 = (N + 1 + 127) & ~127;
    int* deg = (int*)w;                     w += (size_t)padN * 4;
    int* offsets = (int*)w;                 w += (size_t)padN1 * 4;
    int* cur = (int*)w;                     w += (size_t)padN * 4;
    float* dinv = (float*)w;                w += (size_t)padN * 4;
    int* flag = (int*)w;                    w += 512;
    uint32_t* hb = (uint32_t*)w;            w += (size_t)N * (NCH / 2) * 4;  // bf16 h
    uint32_t* entries = (uint32_t*)w;       w += (size_t)E * 4;
    (void)ws_size;

    hipMemsetAsync(deg, 0, (size_t)N * 4, stream);
    detect_idx64_kernel<<<1, 64, 0, stream>>>(ei, flag);

    histo_kernel<<<2048, 256, 0, stream>>>(ei, E, flag, deg);
    scan_prep_kernel<<<1, 1024, 0, stream>>>(deg, N, offsets, cur, dinv);
    build_csr_kernel<<<2048, 256, 0, stream>>>(ei, E, flag, dinv, cur, entries);

    gemm_xw_kernel<<<(N + 15) / 16, 256, 0, stream>>>(x, W, hb, N);

    spmm_csr_kernel<<<(N + 3) / 4, 256, 0, stream>>>(hb, entries, offsets, dinv, bias, out, N);
}

// Round 3
// 331.545 us; speedup vs baseline: 1.6094x; 1.3623x over previous
//
#include <hip/hip_runtime.h>
#include <hip/hip_fp16.h>
#include <stdint.h>

#define NCH 128          // C_IN == C_OUT == 128
#define SCAN_ITEMS 4
#define SCAN_BLOCK 256
#define SCAN_TILE (SCAN_ITEMS * SCAN_BLOCK)   // 1024 elements per block

// ---------------------------------------------------------------------------
// bf16 helpers (manual RNE pack; decode via bit shift)
// ---------------------------------------------------------------------------
__device__ __forceinline__ unsigned short f2bf(float f) {
    union { float f; uint32_t u; } v; v.f = f;
    uint32_t u = v.u;
    uint32_t r = u + 0x7fffu + ((u >> 16) & 1u);
    return (unsigned short)(r >> 16);
}
__device__ __forceinline__ float bflo(uint32_t u) { return __uint_as_float(u << 16); }
__device__ __forceinline__ float bfhi(uint32_t u) { return __uint_as_float(u & 0xffff0000u); }

// ---------------------------------------------------------------------------
// Detect whether edge_index buffer is int64 (odd int32 words all zero) or int32.
// ---------------------------------------------------------------------------
__global__ void detect_idx64_kernel(const int* __restrict__ ei, int* __restrict__ flag) {
    if (blockIdx.x == 0 && threadIdx.x == 0) {
        int nz = 0;
        for (int i = 0; i < 128; ++i) nz |= ei[2 * i + 1];
        *flag = (nz == 0) ? 1 : 0;
    }
}

__device__ __forceinline__ int load_row(const int* ei, int E, int e, bool is64) {
    return is64 ? ei[2 * (size_t)e] : ei[e];
}
__device__ __forceinline__ int load_col(const int* ei, int E, int e, bool is64) {
    return is64 ? ei[2 * (size_t)E + 2 * (size_t)e] : ei[(size_t)E + e];
}

// ---------------------------------------------------------------------------
// Histogram of target (col) nodes.
// ---------------------------------------------------------------------------
__global__ void histo_kernel(const int* __restrict__ ei, int E,
                             const int* __restrict__ flag, int* __restrict__ deg) {
    const bool is64 = (*flag != 0);
    int i = blockIdx.x * blockDim.x + threadIdx.x;
    const int stride = gridDim.x * blockDim.x;
    for (; i < E; i += stride) {
        int c = load_col(ei, E, i, is64);
        atomicAdd(&deg[c], 1);
    }
}

// ---------------------------------------------------------------------------
// Hierarchical scan, stage 1: per-block sums of deg (1024 elems / block).
// ---------------------------------------------------------------------------
__global__ __launch_bounds__(SCAN_BLOCK) void scan_partials_kernel(const int* __restrict__ deg,
                                                                   int N, int* __restrict__ bsum) {
    const int t = threadIdx.x;
    const int base = blockIdx.x * SCAN_TILE + t * SCAN_ITEMS;
    int s = 0;
    #pragma unroll
    for (int j = 0; j < SCAN_ITEMS; ++j) {
        int i = base + j;
        if (i < N) s += deg[i];
    }
    __shared__ int red[SCAN_BLOCK];
    red[t] = s;
    __syncthreads();
    for (int d = SCAN_BLOCK / 2; d > 0; d >>= 1) {
        if (t < d) red[t] += red[t + d];
        __syncthreads();
    }
    if (t == 0) bsum[blockIdx.x] = red[0];
}

// ---------------------------------------------------------------------------
// Stage 2: exclusive scan of block sums (single wave, shfl-based, any nb).
// ---------------------------------------------------------------------------
__global__ void scan_bsums_kernel(int* __restrict__ bsum, int nb) {
    const int t = threadIdx.x;  // 0..63
    int carry = 0;
    for (int base = 0; base < nb; base += 64) {
        const int i = base + t;
        const int orig = (i < nb) ? bsum[i] : 0;
        int v = orig;
        for (int d = 1; d < 64; d <<= 1) {
            int u = __shfl_up(v, d);
            if (t >= d) v += u;
        }
        if (i < nb) bsum[i] = carry + v - orig;  // exclusive
        carry += __shfl(v, 63);
    }
}

// ---------------------------------------------------------------------------
// Stage 3: block-level exclusive scan + write offsets / cur / dinv.
// ---------------------------------------------------------------------------
__global__ __launch_bounds__(SCAN_BLOCK) void scan_write_kernel(const int* __restrict__ deg, int N,
                                                                const int* __restrict__ bofs,
                                                                int* __restrict__ offsets,
                                                                int* __restrict__ cur,
                                                                float* __restrict__ dinv) {
    const int t = threadIdx.x;
    const int base = blockIdx.x * SCAN_TILE + t * SCAN_ITEMS;
    int v[SCAN_ITEMS];
    int s = 0;
    #pragma unroll
    for (int j = 0; j < SCAN_ITEMS; ++j) {
        int i = base + j;
        v[j] = (i < N) ? deg[i] : 0;
        s += v[j];
    }
    __shared__ int sm[SCAN_BLOCK];
    sm[t] = s;
    __syncthreads();
    for (int d = 1; d < SCAN_BLOCK; d <<= 1) {
        int u = (t >= d) ? sm[t - d] : 0;
        __syncthreads();
        sm[t] += u;
        __syncthreads();
    }
    int run = bofs[blockIdx.x] + sm[t] - s;  // exclusive prefix of this thread
    #pragma unroll
    for (int j = 0; j < SCAN_ITEMS; ++j) {
        int i = base + j;
        if (i < N) {
            offsets[i] = run;
            cur[i] = run;
            dinv[i] = rsqrtf((float)(v[j] + 1));
            run += v[j];
        }
    }
    if (blockIdx.x == gridDim.x - 1 && t == SCAN_BLOCK - 1) offsets[N] = run;  // == E
}

// ---------------------------------------------------------------------------
// Scatter edges into CSR order (by target). Entry packs {src:16 | fp16 norm:16}.
// Requires N < 65536 (N = 50000 here).
// ---------------------------------------------------------------------------
__global__ void build_csr_kernel(const int* __restrict__ ei, int E,
                                 const int* __restrict__ flag,
                                 const float* __restrict__ dinv,
                                 int* __restrict__ cur, uint32_t* __restrict__ entries) {
    const bool is64 = (*flag != 0);
    int i = blockIdx.x * blockDim.x + threadIdx.x;
    const int stride = gridDim.x * blockDim.x;
    for (; i < E; i += stride) {
        int r = load_row(ei, E, i, is64);
        int c = load_col(ei, E, i, is64);
        float nrm = dinv[r] * dinv[c];
        uint32_t packed = (uint32_t)r |
            ((uint32_t)__half_as_ushort(__float2half(nrm)) << 16);
        int pos = atomicAdd(&cur[c], 1);
        entries[pos] = packed;
    }
}

// ---------------------------------------------------------------------------
// h = x @ W (f32 compute), stored as bf16. W (64 KiB) staged in LDS.
// ---------------------------------------------------------------------------
__global__ __launch_bounds__(256) void gemm_xw_kernel(const float* __restrict__ x,
                                                      const float* __restrict__ W,
                                                      uint32_t* __restrict__ hb, int N) {
    __shared__ float sW[NCH * NCH];
    for (int i = threadIdx.x * 4; i < NCH * NCH; i += blockDim.x * 4) {
        *reinterpret_cast<float4*>(&sW[i]) = *reinterpret_cast<const float4*>(&W[i]);
    }
    __syncthreads();

    const int wave = threadIdx.x >> 6;
    const int lane = threadIdx.x & 63;
    const int r0 = (blockIdx.x * 4 + wave) * 4;
    if (r0 >= N) return;

    const int ra = min(r0 + 0, N - 1);
    const int rb = min(r0 + 1, N - 1);
    const int rc = min(r0 + 2, N - 1);
    const int rd = min(r0 + 3, N - 1);
    const float* x0 = x + (size_t)ra * NCH;
    const float* x1 = x + (size_t)rb * NCH;
    const float* x2 = x + (size_t)rc * NCH;
    const float* x3 = x + (size_t)rd * NCH;

    float a0x = 0.f, a0y = 0.f, a1x = 0.f, a1y = 0.f;
    float a2x = 0.f, a2y = 0.f, a3x = 0.f, a3y = 0.f;

    #pragma unroll 8
    for (int kk = 0; kk < NCH; kk += 4) {
        const float4 xa = *reinterpret_cast<const float4*>(x0 + kk);
        const float4 xb = *reinterpret_cast<const float4*>(x1 + kk);
        const float4 xc = *reinterpret_cast<const float4*>(x2 + kk);
        const float4 xd = *reinterpret_cast<const float4*>(x3 + kk);
        const float2* wrow = reinterpret_cast<const float2*>(&sW[(size_t)kk * NCH]) + lane;

        float2 w;
        w = wrow[0];
        a0x += xa.x * w.x; a0y += xa.x * w.y;
        a1x += xb.x * w.x; a1y += xb.x * w.y;
        a2x += xc.x * w.x; a2y += xc.x * w.y;
        a3x += xd.x * w.x; a3y += xd.x * w.y;
        w = wrow[NCH / 2];
        a0x += xa.y * w.x; a0y += xa.y * w.y;
        a1x += xb.y * w.x; a1y += xb.y * w.y;
        a2x += xc.y * w.x; a2y += xc.y * w.y;
        a3x += xd.y * w.x; a3y += xd.y * w.y;
        w = wrow[2 * (NCH / 2)];
        a0x += xa.z * w.x; a0y += xa.z * w.y;
        a1x += xb.z * w.x; a1y += xb.z * w.y;
        a2x += xc.z * w.x; a2y += xc.z * w.y;
        a3x += xd.z * w.x; a3y += xd.z * w.y;
        w = wrow[3 * (NCH / 2)];
        a0x += xa.w * w.x; a0y += xa.w * w.y;
        a1x += xb.w * w.x; a1y += xb.w * w.y;
        a2x += xc.w * w.x; a2y += xc.w * w.y;
        a3x += xd.w * w.x; a3y += xd.w * w.y;
    }

    const uint32_t p0 = (uint32_t)f2bf(a0x) | ((uint32_t)f2bf(a0y) << 16);
    const uint32_t p1 = (uint32_t)f2bf(a1x) | ((uint32_t)f2bf(a1y) << 16);
    const uint32_t p2 = (uint32_t)f2bf(a2x) | ((uint32_t)f2bf(a2y) << 16);
    const uint32_t p3 = (uint32_t)f2bf(a3x) | ((uint32_t)f2bf(a3y) << 16);
    if (r0 + 0 < N) hb[(size_t)(r0 + 0) * (NCH / 2) + lane] = p0;
    if (r0 + 1 < N) hb[(size_t)(r0 + 1) * (NCH / 2) + lane] = p1;
    if (r0 + 2 < N) hb[(size_t)(r0 + 2) * (NCH / 2) + lane] = p2;
    if (r0 + 3 < N) hb[(size_t)(r0 + 3) * (NCH / 2) + lane] = p3;
}

// ---------------------------------------------------------------------------
// SpMM: one wave per target node, split into two 32-lane halves.
// ---------------------------------------------------------------------------
__global__ __launch_bounds__(256) void spmm_csr_kernel(const uint32_t* __restrict__ hb,
                                                       const uint32_t* __restrict__ entries,
                                                       const int* __restrict__ offsets,
                                                       const float* __restrict__ dinv,
                                                       const float* __restrict__ bias,
                                                       float* __restrict__ out, int N) {
    const int lane = threadIdx.x & 63;
    const int n = blockIdx.x * 4 + (threadIdx.x >> 6);
    if (n >= N) return;

    const int half = lane >> 5;
    const int sl = lane & 31;          // covers cols sl*4 .. sl*4+3

    const int beg = offsets[n];
    const int end = offsets[n + 1];
    const int len = end - beg;
    const int mid = beg + ((len + 1) >> 1);
    int i = half ? mid : beg;
    const int ie = half ? end : mid;

    float a0 = 0.f, a1 = 0.f, a2 = 0.f, a3 = 0.f;

    for (; i + 3 < ie; i += 4) {
        const uint32_t e0 = entries[i + 0];
        const uint32_t e1 = entries[i + 1];
        const uint32_t e2 = entries[i + 2];
        const uint32_t e3 = entries[i + 3];
        const uint2 u0 = *reinterpret_cast<const uint2*>(hb + (size_t)(e0 & 0xffffu) * (NCH / 2) + sl * 2);
        const uint2 u1 = *reinterpret_cast<const uint2*>(hb + (size_t)(e1 & 0xffffu) * (NCH / 2) + sl * 2);
        const uint2 u2 = *reinterpret_cast<const uint2*>(hb + (size_t)(e2 & 0xffffu) * (NCH / 2) + sl * 2);
        const uint2 u3 = *reinterpret_cast<const uint2*>(hb + (size_t)(e3 & 0xffffu) * (NCH / 2) + sl * 2);
        const float n0 = __half2float(__ushort_as_half((unsigned short)(e0 >> 16)));
        const float n1 = __half2float(__ushort_as_half((unsigned short)(e1 >> 16)));
        const float n2 = __half2float(__ushort_as_half((unsigned short)(e2 >> 16)));
        const float n3 = __half2float(__ushort_as_half((unsigned short)(e3 >> 16)));
        a0 += n0 * bflo(u0.x); a1 += n0 * bfhi(u0.x); a2 += n0 * bflo(u0.y); a3 += n0 * bfhi(u0.y);
        a0 += n1 * bflo(u1.x); a1 += n1 * bfhi(u1.x); a2 += n1 * bflo(u1.y); a3 += n1 * bfhi(u1.y);
        a0 += n2 * bflo(u2.x); a1 += n2 * bfhi(u2.x); a2 += n2 * bflo(u2.y); a3 += n2 * bfhi(u2.y);
        a0 += n3 * bflo(u3.x); a1 += n3 * bfhi(u3.x); a2 += n3 * bflo(u3.y); a3 += n3 * bfhi(u3.y);
    }
    for (; i < ie; ++i) {
        const uint32_t e0 = entries[i];
        const uint2 u0 = *reinterpret_cast<const uint2*>(hb + (size_t)(e0 & 0xffffu) * (NCH / 2) + sl * 2);
        const float n0 = __half2float(__ushort_as_half((unsigned short)(e0 >> 16)));
        a0 += n0 * bflo(u0.x); a1 += n0 * bfhi(u0.x); a2 += n0 * bflo(u0.y); a3 += n0 * bfhi(u0.y);
    }

    a0 += __shfl_xor(a0, 32);
    a1 += __shfl_xor(a1, 32);
    a2 += __shfl_xor(a2, 32);
    a3 += __shfl_xor(a3, 32);

    const float s = dinv[n];
    const float sn = s * s;
    const uint2 us = *reinterpret_cast<const uint2*>(hb + (size_t)n * (NCH / 2) + sl * 2);
    a0 += sn * bflo(us.x); a1 += sn * bfhi(us.x); a2 += sn * bflo(us.y); a3 += sn * bfhi(us.y);

    if (half == 0) {
        const float4 bb = reinterpret_cast<const float4*>(bias)[sl];
        float4 o;
        o.x = fmaxf(a0 + bb.x, 0.f);
        o.y = fmaxf(a1 + bb.y, 0.f);
        o.z = fmaxf(a2 + bb.z, 0.f);
        o.w = fmaxf(a3 + bb.w, 0.f);
        reinterpret_cast<float4*>(out + (size_t)n * NCH)[sl] = o;
    }
}

// ---------------------------------------------------------------------------
extern "C" void kernel_launch(void* const* d_in, const int* in_sizes, int n_in,
                              void* d_out, int out_size, void* d_ws, size_t ws_size,
                              hipStream_t stream) {
    const float* x = (const float*)d_in[0];
    const int* ei = (const int*)d_in[1];  // int32 view; int64 handled via flag
    const float* W = (const float*)d_in[2];
    const float* bias = (const float*)d_in[3];
    float* out = (float*)d_out;

    const int N = in_sizes[0] / NCH;       // 50000
    const int E = in_sizes[1] / 2;         // 1600000

    char* w = (char*)d_ws;
    const int padN = (N + 127) & ~127;
    const int padN1 = (N + 1 + 127) & ~127;
    const int nScanBlocks = (N + SCAN_TILE - 1) / SCAN_TILE;
    const int padB = (nScanBlocks + 127) & ~127;
    int* deg = (int*)w;                     w += (size_t)padN * 4;
    int* offsets = (int*)w;                 w += (size_t)padN1 * 4;
    int* cur = (int*)w;                     w += (size_t)padN * 4;
    float* dinv = (float*)w;                w += (size_t)padN * 4;
    int* bsum = (int*)w;                    w += (size_t)padB * 4;
    int* flag = (int*)w;                    w += 512;
    uint32_t* hb = (uint32_t*)w;            w += (size_t)N * (NCH / 2) * 4;  // bf16 h
    uint32_t* entries = (uint32_t*)w;       w += (size_t)E * 4;
    (void)ws_size;

    hipMemsetAsync(deg, 0, (size_t)N * 4, stream);
    detect_idx64_kernel<<<1, 64, 0, stream>>>(ei, flag);

    histo_kernel<<<2048, 256, 0, stream>>>(ei, E, flag, deg);

    scan_partials_kernel<<<nScanBlocks, SCAN_BLOCK, 0, stream>>>(deg, N, bsum);
    scan_bsums_kernel<<<1, 64, 0, stream>>>(bsum, nScanBlocks);
    scan_write_kernel<<<nScanBlocks, SCAN_BLOCK, 0, stream>>>(deg, N, bsum, offsets, cur, dinv);

    build_csr_kernel<<<2048, 256, 0, stream>>>(ei, E, flag, dinv, cur, entries);

    gemm_xw_kernel<<<(N + 15) / 16, 256, 0, stream>>>(x, W, hb, N);

    spmm_csr_kernel<<<(N + 3) / 4, 256, 0, stream>>>(hb, entries, offsets, dinv, bias, out, N);
}

// Round 4
// 274.325 us; speedup vs baseline: 1.9451x; 1.2086x over previous
//
#include <hip/hip_runtime.h>
#include <hip/hip_fp16.h>
#include <stdint.h>

#define NCH 128          // C_IN == C_OUT == 128
#define SCAN_ITEMS 4
#define SCAN_BLOCK 256
#define SCAN_TILE (SCAN_ITEMS * SCAN_BLOCK)   // 1024 elements per block

typedef short bf16x8 __attribute__((ext_vector_type(8)));
typedef float f32x4 __attribute__((ext_vector_type(4)));

// ---------------------------------------------------------------------------
// bf16 helpers (manual RNE pack; decode via bit shift)
// ---------------------------------------------------------------------------
__device__ __forceinline__ unsigned short f2bf(float f) {
    union { float f; uint32_t u; } v; v.f = f;
    uint32_t u = v.u;
    uint32_t r = u + 0x7fffu + ((u >> 16) & 1u);
    return (unsigned short)(r >> 16);
}
__device__ __forceinline__ float bf2f(unsigned short h) {
    return __uint_as_float((uint32_t)h << 16);
}
__device__ __forceinline__ float bflo(uint32_t u) { return __uint_as_float(u << 16); }
__device__ __forceinline__ float bfhi(uint32_t u) { return __uint_as_float(u & 0xffff0000u); }

// ---------------------------------------------------------------------------
// Detect whether edge_index buffer is int64 (odd int32 words all zero) or int32.
// ---------------------------------------------------------------------------
__global__ void detect_idx64_kernel(const int* __restrict__ ei, int* __restrict__ flag) {
    if (blockIdx.x == 0 && threadIdx.x == 0) {
        int nz = 0;
        for (int i = 0; i < 128; ++i) nz |= ei[2 * i + 1];
        *flag = (nz == 0) ? 1 : 0;
    }
}

__device__ __forceinline__ int load_row(const int* ei, int E, int e, bool is64) {
    return is64 ? ei[2 * (size_t)e] : ei[e];
}
__device__ __forceinline__ int load_col(const int* ei, int E, int e, bool is64) {
    return is64 ? ei[2 * (size_t)E + 2 * (size_t)e] : ei[(size_t)E + e];
}

// ---------------------------------------------------------------------------
// Histogram of target (col) nodes.
// ---------------------------------------------------------------------------
__global__ void histo_kernel(const int* __restrict__ ei, int E,
                             const int* __restrict__ flag, int* __restrict__ deg) {
    const bool is64 = (*flag != 0);
    int i = blockIdx.x * blockDim.x + threadIdx.x;
    const int stride = gridDim.x * blockDim.x;
    for (; i < E; i += stride) {
        int c = load_col(ei, E, i, is64);
        atomicAdd(&deg[c], 1);
    }
}

// ---------------------------------------------------------------------------
// Hierarchical scan, stage 1: per-block sums of deg (1024 elems / block).
// ---------------------------------------------------------------------------
__global__ __launch_bounds__(SCAN_BLOCK) void scan_partials_kernel(const int* __restrict__ deg,
                                                                   int N, int* __restrict__ bsum) {
    const int t = threadIdx.x;
    const int base = blockIdx.x * SCAN_TILE + t * SCAN_ITEMS;
    int s = 0;
    #pragma unroll
    for (int j = 0; j < SCAN_ITEMS; ++j) {
        int i = base + j;
        if (i < N) s += deg[i];
    }
    __shared__ int red[SCAN_BLOCK];
    red[t] = s;
    __syncthreads();
    for (int d = SCAN_BLOCK / 2; d > 0; d >>= 1) {
        if (t < d) red[t] += red[t + d];
        __syncthreads();
    }
    if (t == 0) bsum[blockIdx.x] = red[0];
}

// ---------------------------------------------------------------------------
// Stage 2: exclusive scan of block sums (single wave, shfl-based, any nb).
// ---------------------------------------------------------------------------
__global__ void scan_bsums_kernel(int* __restrict__ bsum, int nb) {
    const int t = threadIdx.x;  // 0..63
    int carry = 0;
    for (int base = 0; base < nb; base += 64) {
        const int i = base + t;
        const int orig = (i < nb) ? bsum[i] : 0;
        int v = orig;
        for (int d = 1; d < 64; d <<= 1) {
            int u = __shfl_up(v, d);
            if (t >= d) v += u;
        }
        if (i < nb) bsum[i] = carry + v - orig;  // exclusive
        carry += __shfl(v, 63);
    }
}

// ---------------------------------------------------------------------------
// Stage 3: block-level exclusive scan + write offsets / cur / dinv.
// ---------------------------------------------------------------------------
__global__ __launch_bounds__(SCAN_BLOCK) void scan_write_kernel(const int* __restrict__ deg, int N,
                                                                const int* __restrict__ bofs,
                                                                int* __restrict__ offsets,
                                                                int* __restrict__ cur,
                                                                float* __restrict__ dinv) {
    const int t = threadIdx.x;
    const int base = blockIdx.x * SCAN_TILE + t * SCAN_ITEMS;
    int v[SCAN_ITEMS];
    int s = 0;
    #pragma unroll
    for (int j = 0; j < SCAN_ITEMS; ++j) {
        int i = base + j;
        v[j] = (i < N) ? deg[i] : 0;
        s += v[j];
    }
    __shared__ int sm[SCAN_BLOCK];
    sm[t] = s;
    __syncthreads();
    for (int d = 1; d < SCAN_BLOCK; d <<= 1) {
        int u = (t >= d) ? sm[t - d] : 0;
        __syncthreads();
        sm[t] += u;
        __syncthreads();
    }
    int run = bofs[blockIdx.x] + sm[t] - s;  // exclusive prefix of this thread
    #pragma unroll
    for (int j = 0; j < SCAN_ITEMS; ++j) {
        int i = base + j;
        if (i < N) {
            offsets[i] = run;
            cur[i] = run;
            dinv[i] = rsqrtf((float)(v[j] + 1));
            run += v[j];
        }
    }
    if (blockIdx.x == gridDim.x - 1 && t == SCAN_BLOCK - 1) offsets[N] = run;  // == E
}

// ---------------------------------------------------------------------------
// Scatter edges into CSR order (by target). Entry packs {src:16 | fp16 norm:16}.
// ---------------------------------------------------------------------------
__global__ void build_csr_kernel(const int* __restrict__ ei, int E,
                                 const int* __restrict__ flag,
                                 const float* __restrict__ dinv,
                                 int* __restrict__ cur, uint32_t* __restrict__ entries) {
    const bool is64 = (*flag != 0);
    int i = blockIdx.x * blockDim.x + threadIdx.x;
    const int stride = gridDim.x * blockDim.x;
    for (; i < E; i += stride) {
        int r = load_row(ei, E, i, is64);
        int c = load_col(ei, E, i, is64);
        float nrm = dinv[r] * dinv[c];
        uint32_t packed = (uint32_t)r |
            ((uint32_t)__half_as_ushort(__float2half(nrm)) << 16);
        int pos = atomicAdd(&cur[c], 1);
        entries[pos] = packed;
    }
}

// ---------------------------------------------------------------------------
// h = x @ W via MFMA bf16 with 3-term split (near-f32 accuracy):
//   h ~= xh*Wh + xl*Wh + xh*Wl   (xl = bf16(x - xh), etc.)
// W staged per-block in LDS, pre-swizzled into mfma_16x16x32 B-fragment order
// so each fragment is a single ds_read_b128.
// Block = 256 threads = 4 waves; block covers 64 rows; wave w -> rows +16w.
// Output packed to bf16 pairs (shfl_xor(1)) into hb [row][64 x uint32].
// ---------------------------------------------------------------------------
__global__ __launch_bounds__(256) void gemm_xw_mfma_kernel(const float* __restrict__ x,
                                                           const float* __restrict__ W,
                                                           uint32_t* __restrict__ hb, int N) {
    // [hl][kt][ct][lane][e]  bf16 -> 2*4*8*64*8*2 = 65536 B
    __shared__ short sW[2][4][8][64][8];
    const int t = threadIdx.x;

    // ---- stage W (f32 -> bf16 hi/lo, fragment-swizzled) ----
    {
        const int n = t & 127;        // output column
        const int hseg = t >> 7;      // 0..1, splits the 16 k-octets
        const int ct = n >> 4;
        const int l16 = n & 15;
        for (int ko = hseg * 8; ko < hseg * 8 + 8; ++ko) {   // k-octet index 0..15
            const int kt = ko >> 2;
            const int g = ko & 3;
            bf16x8 vh, vl;
            #pragma unroll
            for (int e = 0; e < 8; ++e) {
                const float w = W[(size_t)(ko * 8 + e) * NCH + n];
                const unsigned short wh = f2bf(w);
                const float rem = w - bf2f(wh);
                vh[e] = (short)wh;
                vl[e] = (short)f2bf(rem);
            }
            *reinterpret_cast<bf16x8*>(&sW[0][kt][ct][g * 16 + l16][0]) = vh;
            *reinterpret_cast<bf16x8*>(&sW[1][kt][ct][g * 16 + l16][0]) = vl;
        }
    }
    __syncthreads();

    const int wave = t >> 6;
    const int lane = t & 63;
    const int g = lane >> 4;      // k-group
    const int l16 = lane & 15;
    const int row0 = blockIdx.x * 64 + wave * 16;
    if (row0 >= N) return;
    const int arow = min(row0 + l16, N - 1);

    // ---- build A fragments (xh, xl) from f32 x ----
    bf16x8 ah[4], al[4];
    const float* xr = x + (size_t)arow * NCH + g * 8;
    #pragma unroll
    for (int kt = 0; kt < 4; ++kt) {
        const float4 v0 = *reinterpret_cast<const float4*>(xr + kt * 32);
        const float4 v1 = *reinterpret_cast<const float4*>(xr + kt * 32 + 4);
        const float vv[8] = {v0.x, v0.y, v0.z, v0.w, v1.x, v1.y, v1.z, v1.w};
        #pragma unroll
        for (int e = 0; e < 8; ++e) {
            const unsigned short h16 = f2bf(vv[e]);
            const float rem = vv[e] - bf2f(h16);
            ah[kt][e] = (short)h16;
            al[kt][e] = (short)f2bf(rem);
        }
    }

    // ---- MFMA over 8 column-tiles ----
    #pragma unroll
    for (int ct = 0; ct < 8; ++ct) {
        f32x4 acc = {0.f, 0.f, 0.f, 0.f};
        #pragma unroll
        for (int kt = 0; kt < 4; ++kt) {
            const bf16x8 bh = *reinterpret_cast<const bf16x8*>(&sW[0][kt][ct][lane][0]);
            const bf16x8 bl = *reinterpret_cast<const bf16x8*>(&sW[1][kt][ct][lane][0]);
            acc = __builtin_amdgcn_mfma_f32_16x16x32_bf16(ah[kt], bh, acc, 0, 0, 0);
            acc = __builtin_amdgcn_mfma_f32_16x16x32_bf16(al[kt], bh, acc, 0, 0, 0);
            acc = __builtin_amdgcn_mfma_f32_16x16x32_bf16(ah[kt], bl, acc, 0, 0, 0);
        }
        // C/D: col = ct*16 + (lane&15), row = row0 + (lane>>4)*4 + r
        #pragma unroll
        for (int r = 0; r < 4; ++r) {
            const float v = acc[r];
            const float o = __shfl_xor(v, 1);
            const int wrow = row0 + g * 4 + r;
            if ((lane & 1) == 0 && wrow < N) {
                const uint32_t p = (uint32_t)f2bf(v) | ((uint32_t)f2bf(o) << 16);
                hb[(size_t)wrow * (NCH / 2) + ct * 8 + (l16 >> 1)] = p;
            }
        }
    }
}

// ---------------------------------------------------------------------------
// SpMM: one wave per target node, split into two 32-lane halves.
// ---------------------------------------------------------------------------
__global__ __launch_bounds__(256) void spmm_csr_kernel(const uint32_t* __restrict__ hb,
                                                       const uint32_t* __restrict__ entries,
                                                       const int* __restrict__ offsets,
                                                       const float* __restrict__ dinv,
                                                       const float* __restrict__ bias,
                                                       float* __restrict__ out, int N) {
    const int lane = threadIdx.x & 63;
    const int n = blockIdx.x * 4 + (threadIdx.x >> 6);
    if (n >= N) return;

    const int half = lane >> 5;
    const int sl = lane & 31;          // covers cols sl*4 .. sl*4+3

    const int beg = offsets[n];
    const int end = offsets[n + 1];
    const int len = end - beg;
    const int mid = beg + ((len + 1) >> 1);
    int i = half ? mid : beg;
    const int ie = half ? end : mid;

    float a0 = 0.f, a1 = 0.f, a2 = 0.f, a3 = 0.f;

    for (; i + 3 < ie; i += 4) {
        const uint32_t e0 = entries[i + 0];
        const uint32_t e1 = entries[i + 1];
        const uint32_t e2 = entries[i + 2];
        const uint32_t e3 = entries[i + 3];
        const uint2 u0 = *reinterpret_cast<const uint2*>(hb + (size_t)(e0 & 0xffffu) * (NCH / 2) + sl * 2);
        const uint2 u1 = *reinterpret_cast<const uint2*>(hb + (size_t)(e1 & 0xffffu) * (NCH / 2) + sl * 2);
        const uint2 u2 = *reinterpret_cast<const uint2*>(hb + (size_t)(e2 & 0xffffu) * (NCH / 2) + sl * 2);
        const uint2 u3 = *reinterpret_cast<const uint2*>(hb + (size_t)(e3 & 0xffffu) * (NCH / 2) + sl * 2);
        const float n0 = __half2float(__ushort_as_half((unsigned short)(e0 >> 16)));
        const float n1 = __half2float(__ushort_as_half((unsigned short)(e1 >> 16)));
        const float n2 = __half2float(__ushort_as_half((unsigned short)(e2 >> 16)));
        const float n3 = __half2float(__ushort_as_half((unsigned short)(e3 >> 16)));
        a0 += n0 * bflo(u0.x); a1 += n0 * bfhi(u0.x); a2 += n0 * bflo(u0.y); a3 += n0 * bfhi(u0.y);
        a0 += n1 * bflo(u1.x); a1 += n1 * bfhi(u1.x); a2 += n1 * bflo(u1.y); a3 += n1 * bfhi(u1.y);
        a0 += n2 * bflo(u2.x); a1 += n2 * bfhi(u2.x); a2 += n2 * bflo(u2.y); a3 += n2 * bfhi(u2.y);
        a0 += n3 * bflo(u3.x); a1 += n3 * bfhi(u3.x); a2 += n3 * bflo(u3.y); a3 += n3 * bfhi(u3.y);
    }
    for (; i < ie; ++i) {
        const uint32_t e0 = entries[i];
        const uint2 u0 = *reinterpret_cast<const uint2*>(hb + (size_t)(e0 & 0xffffu) * (NCH / 2) + sl * 2);
        const float n0 = __half2float(__ushort_as_half((unsigned short)(e0 >> 16)));
        a0 += n0 * bflo(u0.x); a1 += n0 * bfhi(u0.x); a2 += n0 * bflo(u0.y); a3 += n0 * bfhi(u0.y);
    }

    a0 += __shfl_xor(a0, 32);
    a1 += __shfl_xor(a1, 32);
    a2 += __shfl_xor(a2, 32);
    a3 += __shfl_xor(a3, 32);

    const float s = dinv[n];
    const float sn = s * s;
    const uint2 us = *reinterpret_cast<const uint2*>(hb + (size_t)n * (NCH / 2) + sl * 2);
    a0 += sn * bflo(us.x); a1 += sn * bfhi(us.x); a2 += sn * bflo(us.y); a3 += sn * bfhi(us.y);

    if (half == 0) {
        const float4 bb = reinterpret_cast<const float4*>(bias)[sl];
        float4 o;
        o.x = fmaxf(a0 + bb.x, 0.f);
        o.y = fmaxf(a1 + bb.y, 0.f);
        o.z = fmaxf(a2 + bb.z, 0.f);
        o.w = fmaxf(a3 + bb.w, 0.f);
        reinterpret_cast<float4*>(out + (size_t)n * NCH)[sl] = o;
    }
}

// ---------------------------------------------------------------------------
extern "C" void kernel_launch(void* const* d_in, const int* in_sizes, int n_in,
                              void* d_out, int out_size, void* d_ws, size_t ws_size,
                              hipStream_t stream) {
    const float* x = (const float*)d_in[0];
    const int* ei = (const int*)d_in[1];  // int32 view; int64 handled via flag
    const float* W = (const float*)d_in[2];
    const float* bias = (const float*)d_in[3];
    float* out = (float*)d_out;

    const int N = in_sizes[0] / NCH;       // 50000
    const int E = in_sizes[1] / 2;         // 1600000

    char* w = (char*)d_ws;
    const int padN = (N + 127) & ~127;
    const int padN1 = (N + 1 + 127) & ~127;
    const int nScanBlocks = (N + SCAN_TILE - 1) / SCAN_TILE;
    const int padB = (nScanBlocks + 127) & ~127;
    int* deg = (int*)w;                     w += (size_t)padN * 4;
    int* offsets = (int*)w;                 w += (size_t)padN1 * 4;
    int* cur = (int*)w;                     w += (size_t)padN * 4;
    float* dinv = (float*)w;                w += (size_t)padN * 4;
    int* bsum = (int*)w;                    w += (size_t)padB * 4;
    int* flag = (int*)w;                    w += 512;
    uint32_t* hb = (uint32_t*)w;            w += (size_t)N * (NCH / 2) * 4;  // bf16 h
    uint32_t* entries = (uint32_t*)w;       w += (size_t)E * 4;
    (void)ws_size;

    hipMemsetAsync(deg, 0, (size_t)N * 4, stream);
    detect_idx64_kernel<<<1, 64, 0, stream>>>(ei, flag);

    histo_kernel<<<2048, 256, 0, stream>>>(ei, E, flag, deg);

    scan_partials_kernel<<<nScanBlocks, SCAN_BLOCK, 0, stream>>>(deg, N, bsum);
    scan_bsums_kernel<<<1, 64, 0, stream>>>(bsum, nScanBlocks);
    scan_write_kernel<<<nScanBlocks, SCAN_BLOCK, 0, stream>>>(deg, N, bsum, offsets, cur, dinv);

    build_csr_kernel<<<2048, 256, 0, stream>>>(ei, E, flag, dinv, cur, entries);

    gemm_xw_mfma_kernel<<<(N + 63) / 64, 256, 0, stream>>>(x, W, hb, N);

    spmm_csr_kernel<<<(N + 3) / 4, 256, 0, stream>>>(hb, entries, offsets, dinv, bias, out, N);
}

// Round 5
// 166.621 us; speedup vs baseline: 3.2024x; 1.6464x over previous
//
#include <hip/hip_runtime.h>
#include <hip/hip_fp16.h>
#include <stdint.h>

#define NCH 128            // C_IN == C_OUT == 128
#define BK_SHIFT 9         // 512 targets per bucket
#define BK_TGTS 512
#define NBUCK_MAX 128
#define PT_EDGES 8192      // edges per partition tile
#define BS_CAP 18432       // bucket_sort LDS capacity (mean 16384, +16 sigma)

typedef short bf16x8 __attribute__((ext_vector_type(8)));
typedef float f32x4 __attribute__((ext_vector_type(4)));

// ---------------------------------------------------------------------------
// bf16 helpers (manual RNE pack; decode via bit shift)
// ---------------------------------------------------------------------------
__device__ __forceinline__ unsigned short f2bf(float f) {
    union { float f; uint32_t u; } v; v.f = f;
    uint32_t u = v.u;
    uint32_t r = u + 0x7fffu + ((u >> 16) & 1u);
    return (unsigned short)(r >> 16);
}
__device__ __forceinline__ float bf2f(unsigned short h) {
    return __uint_as_float((uint32_t)h << 16);
}
__device__ __forceinline__ float bflo(uint32_t u) { return __uint_as_float(u << 16); }
__device__ __forceinline__ float bfhi(uint32_t u) { return __uint_as_float(u & 0xffff0000u); }

// ---------------------------------------------------------------------------
// Detect whether edge_index buffer is int64 (odd int32 words all zero) or int32.
// ---------------------------------------------------------------------------
__global__ void detect_idx64_kernel(const int* __restrict__ ei, int* __restrict__ flag) {
    if (blockIdx.x == 0 && threadIdx.x == 0) {
        int nz = 0;
        for (int i = 0; i < 128; ++i) nz |= ei[2 * i + 1];
        *flag = (nz == 0) ? 1 : 0;
    }
}

__device__ __forceinline__ int load_row(const int* ei, int E, int e, bool is64) {
    return is64 ? ei[2 * (size_t)e] : ei[e];
}
__device__ __forceinline__ int load_col(const int* ei, int E, int e, bool is64) {
    return is64 ? ei[2 * (size_t)E + 2 * (size_t)e] : ei[(size_t)E + e];
}

// ---------------------------------------------------------------------------
// Stage 1: per-bucket edge counts (LDS-aggregated histogram of c >> BK_SHIFT).
// ---------------------------------------------------------------------------
__global__ __launch_bounds__(256) void bucket_count_kernel(const int* __restrict__ ei, int E,
                                                           const int* __restrict__ flag,
                                                           int* __restrict__ bcnt) {
    __shared__ int hist[NBUCK_MAX];
    const bool is64 = (*flag != 0);
    const int t = threadIdx.x;
    for (int i = t; i < NBUCK_MAX; i += 256) hist[i] = 0;
    __syncthreads();
    int i = blockIdx.x * 256 + t;
    const int stride = gridDim.x * 256;
    for (; i < E; i += stride) {
        int c = load_col(ei, E, i, is64);
        atomicAdd(&hist[c >> BK_SHIFT], 1);
    }
    __syncthreads();
    for (int b = t; b < NBUCK_MAX; b += 256) {
        if (hist[b]) atomicAdd(&bcnt[b], hist[b]);
    }
}

// ---------------------------------------------------------------------------
// Stage 2: one-wave exclusive scan of bucket counts -> bbase, init bcur.
// ---------------------------------------------------------------------------
__global__ void bucket_scan_kernel(const int* __restrict__ bcnt, int nbuck,
                                   int* __restrict__ bbase, int* __restrict__ bcur) {
    const int t = threadIdx.x;  // 64
    int carry = 0;
    for (int base = 0; base < nbuck; base += 64) {
        const int i = base + t;
        const int orig = (i < nbuck) ? bcnt[i] : 0;
        int v = orig;
        for (int d = 1; d < 64; d <<= 1) {
            int u = __shfl_up(v, d);
            if (t >= d) v += u;
        }
        if (i < nbuck) { bbase[i] = carry + v - orig; bcur[i] = carry + v - orig; }
        carry += __shfl(v, 63);
    }
    if (t == 0) bbase[nbuck] = carry;  // == E
}

// ---------------------------------------------------------------------------
// Stage 3: partition edges into buckets. Packed entry = {c:16 | r:16}.
// Per-tile LDS histogram gives each edge a local rank; one global atomic per
// (tile,bucket) claims a dense chunk -> near-coalesced frontier writes.
// ---------------------------------------------------------------------------
__global__ __launch_bounds__(256) void partition_kernel(const int* __restrict__ ei, int E,
                                                        const int* __restrict__ flag, int nbuck,
                                                        int* __restrict__ bcur,
                                                        uint32_t* __restrict__ bkt) {
    __shared__ int hist[NBUCK_MAX];
    __shared__ int cbase[NBUCK_MAX];
    __shared__ uint32_t stage[PT_EDGES];
    const bool is64 = (*flag != 0);
    const int t = threadIdx.x;
    const int e0 = blockIdx.x * PT_EDGES;
    const int cnt = min(PT_EDGES, E - e0);

    for (int i = t; i < NBUCK_MAX; i += 256) hist[i] = 0;
    __syncthreads();

    int rank[PT_EDGES / 256];
    #pragma unroll
    for (int j = 0; j < PT_EDGES / 256; ++j) {
        const int i = t + j * 256;
        if (i < cnt) {
            const int r = load_row(ei, E, e0 + i, is64);
            const int c = load_col(ei, E, e0 + i, is64);
            stage[i] = ((uint32_t)c << 16) | (uint32_t)r;
            rank[j] = atomicAdd(&hist[c >> BK_SHIFT], 1);
        }
    }
    __syncthreads();
    for (int b = t; b < nbuck; b += 256) {
        cbase[b] = hist[b] ? atomicAdd(&bcur[b], hist[b]) : 0;
    }
    __syncthreads();
    #pragma unroll
    for (int j = 0; j < PT_EDGES / 256; ++j) {
        const int i = t + j * 256;
        if (i < cnt) {
            const uint32_t p = stage[i];
            const int b = (int)(p >> (16 + BK_SHIFT));
            bkt[cbase[b] + rank[j]] = p;
        }
    }
}

// ---------------------------------------------------------------------------
// Stage 4: one block per bucket. Counting sort in LDS:
//   - 512-target histogram  -> deg, dinv, global CSR offsets
//   - LDS-ranked scatter of u16 src entries into the bucket's private window.
// ---------------------------------------------------------------------------
__global__ __launch_bounds__(256) void bucket_sort_kernel(const uint32_t* __restrict__ bkt,
                                                          const int* __restrict__ bbase,
                                                          int N, int nbuck,
                                                          unsigned short* __restrict__ entries,
                                                          int* __restrict__ offsets,
                                                          float* __restrict__ dinv) {
    __shared__ uint32_t se[BS_CAP];
    __shared__ int hist[BK_TGTS];
    __shared__ int lofs[BK_TGTS];
    __shared__ int sm[256];
    const int b = blockIdx.x;
    const int t = threadIdx.x;
    const int c0 = b << BK_SHIFT;
    const int ntgt = min(BK_TGTS, N - c0);
    const int beg = bbase[b];
    const int nE = bbase[b + 1] - beg;

    for (int i = t; i < BK_TGTS; i += 256) hist[i] = 0;
    __syncthreads();
    for (int i = t; i < nE; i += 256) {
        const uint32_t p = bkt[beg + i];
        se[i] = p;
        atomicAdd(&hist[(int)(p >> 16) - c0], 1);
    }
    __syncthreads();

    // exclusive scan of hist[0..511]: thread t owns elements {2t, 2t+1}
    const int h0 = hist[2 * t], h1 = hist[2 * t + 1];
    sm[t] = h0 + h1;
    __syncthreads();
    for (int d = 1; d < 256; d <<= 1) {
        int u = (t >= d) ? sm[t - d] : 0;
        __syncthreads();
        sm[t] += u;
        __syncthreads();
    }
    const int ex = sm[t] - (h0 + h1);
    lofs[2 * t] = ex;
    lofs[2 * t + 1] = ex + h0;
    __syncthreads();

    // write offsets + dinv for this bucket's targets
    for (int i = t; i < ntgt; i += 256) {
        offsets[c0 + i] = beg + lofs[i];
        dinv[c0 + i] = rsqrtf((float)(hist[i] + 1));
    }
    if (t == 0 && b == nbuck - 1) offsets[N] = bbase[nbuck];
    __syncthreads();

    // reuse hist as scatter cursors
    for (int i = t; i < BK_TGTS; i += 256) hist[i] = lofs[i];
    __syncthreads();
    for (int i = t; i < nE; i += 256) {
        const uint32_t p = se[i];
        const int tgt = (int)(p >> 16) - c0;
        const int pos = atomicAdd(&hist[tgt], 1);
        entries[beg + pos] = (unsigned short)(p & 0xffffu);
    }
}

// ---------------------------------------------------------------------------
// h = x @ W via MFMA bf16, 3-term split; output pre-scaled by dinv[row]:
//   hb[row] = bf16( dinv[row] * (x @ W)[row] )
// ---------------------------------------------------------------------------
__global__ __launch_bounds__(256) void gemm_xw_mfma_kernel(const float* __restrict__ x,
                                                           const float* __restrict__ W,
                                                           const float* __restrict__ dinv,
                                                           uint32_t* __restrict__ hb, int N) {
    __shared__ short sW[2][4][8][64][8];
    const int t = threadIdx.x;

    // ---- stage W (f32 -> bf16 hi/lo, fragment-swizzled) ----
    {
        const int n = t & 127;
        const int hseg = t >> 7;
        const int ct = n >> 4;
        const int l16 = n & 15;
        for (int ko = hseg * 8; ko < hseg * 8 + 8; ++ko) {
            const int kt = ko >> 2;
            const int g = ko & 3;
            bf16x8 vh, vl;
            #pragma unroll
            for (int e = 0; e < 8; ++e) {
                const float w = W[(size_t)(ko * 8 + e) * NCH + n];
                const unsigned short wh = f2bf(w);
                const float rem = w - bf2f(wh);
                vh[e] = (short)wh;
                vl[e] = (short)f2bf(rem);
            }
            *reinterpret_cast<bf16x8*>(&sW[0][kt][ct][g * 16 + l16][0]) = vh;
            *reinterpret_cast<bf16x8*>(&sW[1][kt][ct][g * 16 + l16][0]) = vl;
        }
    }
    __syncthreads();

    const int wave = t >> 6;
    const int lane = t & 63;
    const int g = lane >> 4;
    const int l16 = lane & 15;
    const int row0 = blockIdx.x * 64 + wave * 16;
    if (row0 >= N) return;
    const int arow = min(row0 + l16, N - 1);

    bf16x8 ah[4], al[4];
    const float* xr = x + (size_t)arow * NCH + g * 8;
    #pragma unroll
    for (int kt = 0; kt < 4; ++kt) {
        const float4 v0 = *reinterpret_cast<const float4*>(xr + kt * 32);
        const float4 v1 = *reinterpret_cast<const float4*>(xr + kt * 32 + 4);
        const float vv[8] = {v0.x, v0.y, v0.z, v0.w, v1.x, v1.y, v1.z, v1.w};
        #pragma unroll
        for (int e = 0; e < 8; ++e) {
            const unsigned short h16 = f2bf(vv[e]);
            const float rem = vv[e] - bf2f(h16);
            ah[kt][e] = (short)h16;
            al[kt][e] = (short)f2bf(rem);
        }
    }

    float dn[4];
    #pragma unroll
    for (int r = 0; r < 4; ++r) dn[r] = dinv[min(row0 + g * 4 + r, N - 1)];

    #pragma unroll
    for (int ct = 0; ct < 8; ++ct) {
        f32x4 acc = {0.f, 0.f, 0.f, 0.f};
        #pragma unroll
        for (int kt = 0; kt < 4; ++kt) {
            const bf16x8 bh = *reinterpret_cast<const bf16x8*>(&sW[0][kt][ct][lane][0]);
            const bf16x8 bl = *reinterpret_cast<const bf16x8*>(&sW[1][kt][ct][lane][0]);
            acc = __builtin_amdgcn_mfma_f32_16x16x32_bf16(ah[kt], bh, acc, 0, 0, 0);
            acc = __builtin_amdgcn_mfma_f32_16x16x32_bf16(al[kt], bh, acc, 0, 0, 0);
            acc = __builtin_amdgcn_mfma_f32_16x16x32_bf16(ah[kt], bl, acc, 0, 0, 0);
        }
        #pragma unroll
        for (int r = 0; r < 4; ++r) {
            const float v = acc[r] * dn[r];
            const float o = __shfl_xor(v, 1);
            const int wrow = row0 + g * 4 + r;
            if ((lane & 1) == 0 && wrow < N) {
                const uint32_t p = (uint32_t)f2bf(v) | ((uint32_t)f2bf(o) << 16);
                hb[(size_t)wrow * (NCH / 2) + ct * 8 + (l16 >> 1)] = p;
            }
        }
    }
}

// ---------------------------------------------------------------------------
// SpMM: one wave per target node, two 32-lane halves over the edge list.
// hb rows are pre-scaled by dinv[src]; final scale by dinv[n] once.
// ---------------------------------------------------------------------------
__global__ __launch_bounds__(256) void spmm_csr_kernel(const uint32_t* __restrict__ hb,
                                                       const unsigned short* __restrict__ entries,
                                                       const int* __restrict__ offsets,
                                                       const float* __restrict__ dinv,
                                                       const float* __restrict__ bias,
                                                       float* __restrict__ out, int N) {
    const int lane = threadIdx.x & 63;
    const int n = blockIdx.x * 4 + (threadIdx.x >> 6);
    if (n >= N) return;

    const int half = lane >> 5;
    const int sl = lane & 31;          // covers cols sl*4 .. sl*4+3

    const int beg = offsets[n];
    const int end = offsets[n + 1];
    const int len = end - beg;
    const int mid = beg + ((len + 1) >> 1);
    int i = half ? mid : beg;
    const int ie = half ? end : mid;

    float a0 = 0.f, a1 = 0.f, a2 = 0.f, a3 = 0.f;

    for (; i + 3 < ie; i += 4) {
        const int s0 = entries[i + 0];
        const int s1 = entries[i + 1];
        const int s2 = entries[i + 2];
        const int s3 = entries[i + 3];
        const uint2 u0 = *reinterpret_cast<const uint2*>(hb + (size_t)s0 * (NCH / 2) + sl * 2);
        const uint2 u1 = *reinterpret_cast<const uint2*>(hb + (size_t)s1 * (NCH / 2) + sl * 2);
        const uint2 u2 = *reinterpret_cast<const uint2*>(hb + (size_t)s2 * (NCH / 2) + sl * 2);
        const uint2 u3 = *reinterpret_cast<const uint2*>(hb + (size_t)s3 * (NCH / 2) + sl * 2);
        a0 += bflo(u0.x); a1 += bfhi(u0.x); a2 += bflo(u0.y); a3 += bfhi(u0.y);
        a0 += bflo(u1.x); a1 += bfhi(u1.x); a2 += bflo(u1.y); a3 += bfhi(u1.y);
        a0 += bflo(u2.x); a1 += bfhi(u2.x); a2 += bflo(u2.y); a3 += bfhi(u2.y);
        a0 += bflo(u3.x); a1 += bfhi(u3.x); a2 += bflo(u3.y); a3 += bfhi(u3.y);
    }
    for (; i < ie; ++i) {
        const int s0 = entries[i];
        const uint2 u0 = *reinterpret_cast<const uint2*>(hb + (size_t)s0 * (NCH / 2) + sl * 2);
        a0 += bflo(u0.x); a1 += bfhi(u0.x); a2 += bflo(u0.y); a3 += bfhi(u0.y);
    }

    a0 += __shfl_xor(a0, 32);
    a1 += __shfl_xor(a1, 32);
    a2 += __shfl_xor(a2, 32);
    a3 += __shfl_xor(a3, 32);

    // self-loop: hb[n] is dinv[n]*h[n]
    const uint2 us = *reinterpret_cast<const uint2*>(hb + (size_t)n * (NCH / 2) + sl * 2);
    a0 += bflo(us.x); a1 += bfhi(us.x); a2 += bflo(us.y); a3 += bfhi(us.y);

    const float s = dinv[n];
    if (half == 0) {
        const float4 bb = reinterpret_cast<const float4*>(bias)[sl];
        float4 o;
        o.x = fmaxf(a0 * s + bb.x, 0.f);
        o.y = fmaxf(a1 * s + bb.y, 0.f);
        o.z = fmaxf(a2 * s + bb.z, 0.f);
        o.w = fmaxf(a3 * s + bb.w, 0.f);
        reinterpret_cast<float4*>(out + (size_t)n * NCH)[sl] = o;
    }
}

// ---------------------------------------------------------------------------
extern "C" void kernel_launch(void* const* d_in, const int* in_sizes, int n_in,
                              void* d_out, int out_size, void* d_ws, size_t ws_size,
                              hipStream_t stream) {
    const float* x = (const float*)d_in[0];
    const int* ei = (const int*)d_in[1];  // int32 view; int64 handled via flag
    const float* W = (const float*)d_in[2];
    const float* bias = (const float*)d_in[3];
    float* out = (float*)d_out;

    const int N = in_sizes[0] / NCH;       // 50000
    const int E = in_sizes[1] / 2;         // 1600000
    const int nbuck = (N + BK_TGTS - 1) >> BK_SHIFT;   // 98

    char* w = (char*)d_ws;
    const int padN = (N + 127) & ~127;
    const int padN1 = (N + 1 + 127) & ~127;
    int* offsets = (int*)w;                 w += (size_t)padN1 * 4;
    float* dinv = (float*)w;                w += (size_t)padN * 4;
    int* bcnt = (int*)w;                    w += NBUCK_MAX * 4;
    int* bbase = (int*)w;                   w += (NBUCK_MAX + 128) * 4;
    int* bcur = (int*)w;                    w += NBUCK_MAX * 4;
    int* flag = (int*)w;                    w += 512;
    // regionA: bkt (E*4 = 6.4 MB) while building; hb (N*64*4 = 12.8 MB) after
    uint32_t* bkt = (uint32_t*)w;
    uint32_t* hb = (uint32_t*)w;            w += (size_t)N * (NCH / 2) * 4;
    unsigned short* entries = (unsigned short*)w;  w += (size_t)E * 2;
    (void)ws_size;

    hipMemsetAsync(bcnt, 0, NBUCK_MAX * 4, stream);
    detect_idx64_kernel<<<1, 64, 0, stream>>>(ei, flag);

    bucket_count_kernel<<<1024, 256, 0, stream>>>(ei, E, flag, bcnt);
    bucket_scan_kernel<<<1, 64, 0, stream>>>(bcnt, nbuck, bbase, bcur);
    partition_kernel<<<(E + PT_EDGES - 1) / PT_EDGES, 256, 0, stream>>>(ei, E, flag, nbuck, bcur, bkt);
    bucket_sort_kernel<<<nbuck, 256, 0, stream>>>(bkt, bbase, N, nbuck, entries, offsets, dinv);

    gemm_xw_mfma_kernel<<<(N + 63) / 64, 256, 0, stream>>>(x, W, dinv, hb, N);

    spmm_csr_kernel<<<(N + 3) / 4, 256, 0, stream>>>(hb, entries, offsets, dinv, bias, out, N);
}